// Round 22
// baseline (220.328 us; speedup 1.0000x reference)
//
#include <hip/hip_runtime.h>

#define V_N 30522
#define A_N 2
#define H_N 128
#define O_N 16
#define NNZ_N 250000
#define NNZ_T (A_N * NNZ_N)  // 500000
#define M_N 2048
#define AV_N (A_N * V_N)     // 61044

#define KPAD 30720
#define NCHUNK 30            // ceil(V_N / 1024)
#define PADN ((KPAD - V_N) * O_N)  // 3168 pad entries of hw_kt

#define RB 4                 // rows per wave
#define VKS 8                // K-splits
#define VKC (KPAD / VKS)     // 3840
#define VITER (VKC / 256)    // 15 iters (each consumes 64 lanes * 4 k)

typedef __attribute__((ext_vector_type(8))) short bf16x8_t;

static __device__ __forceinline__ unsigned short f2bf(float f) {
    union { float f; unsigned u; } v; v.f = f;
    unsigned r = v.u + 0x7fffu + ((v.u >> 16) & 1u);   // RNE
    return (unsigned short)(r >> 16);
}

static __device__ __forceinline__ float bf2f(short s) {
    union { unsigned u; float f; } v;
    v.u = ((unsigned)(unsigned short)s) << 16;
    return v.f;
}

// ---------------- Step 0: wfc = W @ fcW  (+ fold: zero count) (R11-verified) ------------
__global__ __launch_bounds__(256) void wfc_kernel(const float* __restrict__ W,
                                                  const float* __restrict__ fcW,
                                                  float* __restrict__ wfc,
                                                  int* __restrict__ count) {
    int gtid = blockIdx.x * 256 + threadIdx.x;
    if (gtid < V_N) count[gtid] = 0;

    __shared__ float wrow[16][128];
    int row0 = blockIdx.x * 16;
    for (int idx = threadIdx.x; idx < 16 * 32; idx += 256) {
        int r = idx >> 5, c4 = (idx & 31) * 4;
        int grow = row0 + r;
        float4 v = make_float4(0.f, 0.f, 0.f, 0.f);
        if (grow < AV_N)
            v = *reinterpret_cast<const float4*>(W + (size_t)grow * H_N + c4);
        *reinterpret_cast<float4*>(&wrow[r][c4]) = v;
    }
    __syncthreads();
    int r = threadIdx.x >> 4, o = threadIdx.x & 15;
    int grow = row0 + r;
    if (grow >= AV_N) return;
    float s = 0.f;
#pragma unroll
    for (int h = 0; h < H_N; ++h) s += wrow[r][h] * fcW[h * O_N + o];
    wfc[(size_t)grow * O_N + o] = s;
}

// ---------------- Step 1: histogram (+ fold: zero hw_kt K-pad) ----------------
__global__ __launch_bounds__(256) void hist_kernel(const int* __restrict__ rows,
                                                   int* __restrict__ count,
                                                   short* __restrict__ hw_kt) {
    int n = blockIdx.x * blockDim.x + threadIdx.x;
    if (n < PADN) hw_kt[(size_t)V_N * O_N + n] = 0;   // rows [V_N, KPAD) zeroed
    if (n >= NNZ_T) return;
    atomicAdd(&count[rows[n]], 1);
}

// ---------------- Step 2a: per-1024-chunk sums (R7-verified) ----------------
__global__ __launch_bounds__(1024) void scanA_kernel(const int* __restrict__ count,
                                                     int* __restrict__ csum) {
    __shared__ int sdata[1024];
    int tid = threadIdx.x;
    int i = blockIdx.x * 1024 + tid;
    sdata[tid] = (i < V_N) ? count[i] : 0;
    __syncthreads();
    for (int off = 512; off > 0; off >>= 1) {
        if (tid < off) sdata[tid] += sdata[tid + off];
        __syncthreads();
    }
    if (tid == 0) csum[blockIdx.x] = sdata[0];
}

// ---------------- Step 2b: per-chunk exclusive scan + folded chunk-offset scan ----------
// (R14-verified)
__global__ __launch_bounds__(1024) void scanC_kernel(const int* __restrict__ count,
                                                     const int* __restrict__ csum,
                                                     int* __restrict__ row_start,
                                                     int* __restrict__ cursor) {
    __shared__ int sdata[1024];
    __shared__ int coff_s;
    int tid = threadIdx.x;
    int bid = blockIdx.x;
    if (tid < 32) {
        int own = (tid < NCHUNK) ? csum[tid] : 0;
        int v = own;
#pragma unroll
        for (int d = 1; d < 32; d <<= 1) {
            int t = __shfl_up(v, d, 32);
            if (tid >= d) v += t;
        }
        if (tid == bid) coff_s = v - own;                      // exclusive prefix
        if (bid == 0 && tid == NCHUNK - 1) row_start[V_N] = v; // total
    }
    int i = bid * 1024 + tid;
    int v = (i < V_N) ? count[i] : 0;
    sdata[tid] = v;
    __syncthreads();
    for (int off = 1; off < 1024; off <<= 1) {
        int t = (tid >= off) ? sdata[tid - off] : 0;
        __syncthreads();
        sdata[tid] += t;
        __syncthreads();
    }
    int exc = sdata[tid] - v + coff_s;
    if (i < V_N) { row_start[i] = exc; cursor[i] = exc; }
}

// ---------------- Step 3: scatter nnz, packed (colp|val) 8B stores (R8-verified) --------
__global__ __launch_bounds__(256) void scatter_kernel(const int* __restrict__ rows,
                                                      const int* __restrict__ cols,
                                                      const float* __restrict__ vals,
                                                      int* __restrict__ cursor,
                                                      unsigned long long* __restrict__ scv) {
    int n = blockIdx.x * blockDim.x + threadIdx.x;
    if (n >= NNZ_T) return;
    int a = (n >= NNZ_N) ? 1 : 0;
    int r = rows[n];
    int pos = atomicAdd(&cursor[r], 1);
    union { float f; unsigned u; } uv; uv.f = vals[n];
    scv[pos] = ((unsigned long long)uv.u << 32) | (unsigned)(a * V_N + cols[n]);
}

// ---------------- Step 4: segmented accumulate -> hw_kt bf16 [KPAD][16] (k-major) -------
// (R8-verified gather logic; only the store layout changes: row-major 16-contiguous)
__global__ __launch_bounds__(256) void accum_hw_kernel(const int* __restrict__ row_start,
                                                       const unsigned long long* __restrict__ scv,
                                                       const float* __restrict__ wfc,
                                                       short* __restrict__ hw_kt) {
    int gid = blockIdx.x * blockDim.x + threadIdx.x;
    if (gid >= V_N * O_N) return;
    int row = gid >> 4, o = gid & 15;
    int s = row_start[row];
    int e = row_start[row + 1];
    float acc = 0.f;
    for (int i = s; i < e; ++i) {
        unsigned long long cv = scv[i];
        int cp = (int)(cv & 0xffffffffu);
        union { unsigned u; float f; } uv; uv.u = (unsigned)(cv >> 32);
        acc += uv.f * wfc[(size_t)cp * O_N + o];
    }
    hw_kt[(size_t)row * O_N + o] = (short)f2bf(acc);
}

// ---------------- Step 5: VALU GEMM, copy-pattern X reads -> partials ----------------
// grid (M_N/RB=512, VKS=8), 64 threads (1 wave). Lanes partition K: lane l owns
// k = k0 + it*256 + l*4 .. +3 — the wave's x reads are 1KB CONTIGUOUS per row (m13
// pattern). hw_kt k-major: each lane reads its own 128B contiguous (L2-resident).
// acc[4][16] f32; X never rounded to bf16. Butterfly-reduce, lanes 0..15 store.
__global__ __launch_bounds__(64) void gemm_valu(const float* __restrict__ X,
                                                const short* __restrict__ hw_kt,
                                                float* __restrict__ partials) {
    const int lane = threadIdx.x;
    const int rg = blockIdx.x;          // row group
    const int ks = blockIdx.y;
    const int row0 = rg * RB;
    const int kbase = ks * VKC + lane * 4;

    float acc[RB][16];
#pragma unroll
    for (int r = 0; r < RB; ++r)
#pragma unroll
        for (int o = 0; o < 16; ++o) acc[r][o] = 0.f;

    for (int it = 0; it < VITER; ++it) {
        const int k = kbase + it * 256;
        // x loads: float2 pairs (rows are only 8B-aligned); contiguous across the wave
        float xv[RB][4];
        if (k + 3 < V_N) {
#pragma unroll
            for (int r = 0; r < RB; ++r) {
                const float2* p = reinterpret_cast<const float2*>(X + (size_t)(row0 + r) * V_N + k);
                float2 u0 = p[0], u1 = p[1];
                xv[r][0] = u0.x; xv[r][1] = u0.y; xv[r][2] = u1.x; xv[r][3] = u1.y;
            }
        } else {
#pragma unroll
            for (int r = 0; r < RB; ++r)
#pragma unroll
                for (int j = 0; j < 4; ++j)
                    xv[r][j] = (k + j < V_N) ? X[(size_t)(row0 + r) * V_N + k + j] : 0.f;
        }
        // hw loads: 128B contiguous per lane = rows k..k+3 of [KPAD][16] bf16
        const short* hp = hw_kt + (size_t)k * O_N;
        bf16x8_t hv[8];
#pragma unroll
        for (int q = 0; q < 8; ++q) hv[q] = *reinterpret_cast<const bf16x8_t*>(hp + q * 8);
        // hv[2j] = hw[k+j][0..7], hv[2j+1] = hw[k+j][8..15]
#pragma unroll
        for (int j = 0; j < 4; ++j) {
            float hwf[16];
#pragma unroll
            for (int i = 0; i < 8; ++i) {
                hwf[i] = bf2f(hv[2 * j][i]);
                hwf[8 + i] = bf2f(hv[2 * j + 1][i]);
            }
#pragma unroll
            for (int r = 0; r < RB; ++r) {
                float xs = xv[r][j];
#pragma unroll
                for (int o = 0; o < 16; ++o) acc[r][o] += xs * hwf[o];
            }
        }
    }

    // butterfly reduce across 64 lanes
#pragma unroll
    for (int r = 0; r < RB; ++r)
#pragma unroll
        for (int o = 0; o < 16; ++o) {
            float v = acc[r][o];
#pragma unroll
            for (int d = 1; d < 64; d <<= 1) v += __shfl_xor(v, d, 64);
            acc[r][o] = v;
        }
    if (lane < 16) {
#pragma unroll
        for (int r = 0; r < RB; ++r)
            partials[((size_t)ks * M_N + row0 + r) * O_N + lane] = acc[r][lane];
    }
}

// ---------------- Step 6: reduce split-K partials + bias -> out ----------------
__global__ __launch_bounds__(256) void reduce_kernel(const float* __restrict__ partials,
                                                     const float* __restrict__ fcb,
                                                     float* __restrict__ out) {
    int idx = blockIdx.x * 256 + threadIdx.x;   // 0 .. M_N*O_N-1
    if (idx >= M_N * O_N) return;
    float s = fcb[idx & 15];
#pragma unroll
    for (int ks = 0; ks < VKS; ++ks)
        s += partials[(size_t)ks * M_N * O_N + idx];
    out[idx] = s;
}

extern "C" void kernel_launch(void* const* d_in, const int* in_sizes, int n_in,
                              void* d_out, int out_size, void* d_ws, size_t ws_size,
                              hipStream_t stream) {
    const float* x    = (const float*)d_in[0];
    const int* rows   = (const int*)d_in[1];
    const int* cols   = (const int*)d_in[2];
    const float* vals = (const float*)d_in[3];
    const float* W    = (const float*)d_in[4];
    const float* fcW  = (const float*)d_in[5];
    const float* fcb  = (const float*)d_in[6];
    float* out = (float*)d_out;

    char* base = (char*)d_ws;
    size_t off = 0;
    auto alloc = [&](size_t bytes) { size_t p = off; off = (off + bytes + 255) & ~(size_t)255; return p; };
    size_t o_wfc    = alloc((size_t)AV_N * O_N * 4);
    size_t o_hwt    = alloc((size_t)KPAD * O_N * 2);
    size_t o_count  = alloc((size_t)V_N * 4);
    size_t o_rstart = alloc((size_t)(V_N + 1) * 4);
    size_t o_cursor = alloc((size_t)V_N * 4);
    size_t o_scv    = alloc((size_t)NNZ_T * 8);
    size_t o_csum   = alloc((size_t)NCHUNK * 4);
    size_t o_part   = alloc((size_t)VKS * M_N * O_N * 4);

    float* wfc        = (float*)(base + o_wfc);
    short* hw_kt      = (short*)(base + o_hwt);
    int*   count      = (int*)(base + o_count);
    int*   row_start  = (int*)(base + o_rstart);
    int*   cursor     = (int*)(base + o_cursor);
    unsigned long long* scv = (unsigned long long*)(base + o_scv);
    int*   csum       = (int*)(base + o_csum);
    float* partials   = (float*)(base + o_part);

    wfc_kernel<<<(AV_N + 15) / 16, 256, 0, stream>>>(W, fcW, wfc, count);
    hist_kernel<<<(NNZ_T + 255) / 256, 256, 0, stream>>>(rows, count, hw_kt);
    scanA_kernel<<<NCHUNK, 1024, 0, stream>>>(count, csum);
    scanC_kernel<<<NCHUNK, 1024, 0, stream>>>(count, csum, row_start, cursor);
    scatter_kernel<<<(NNZ_T + 255) / 256, 256, 0, stream>>>(rows, cols, vals, cursor, scv);
    accum_hw_kernel<<<(V_N * O_N + 255) / 256, 256, 0, stream>>>(row_start, scv, wfc, hw_kt);

    gemm_valu<<<dim3(M_N / RB, VKS), 64, 0, stream>>>(x, hw_kt, partials);
    reduce_kernel<<<(M_N * O_N + 255) / 256, 256, 0, stream>>>(partials, fcb, out);
}

// Round 23
// 158.157 us; speedup vs baseline: 1.3931x; 1.3931x over previous
//
#include <hip/hip_runtime.h>

#define V_N 30522
#define A_N 2
#define H_N 128
#define O_N 16
#define NNZ_N 250000
#define NNZ_T (A_N * NNZ_N)  // 500000
#define M_N 2048
#define AV_N (A_N * V_N)     // 61044

#define KPAD 30720
#define KSPL 16
#define KC (KPAD / KSPL)     // 1920 = 60 steps of 32
#define NSTEP (KC / 32)      // 60
#define NCHUNK 30            // ceil(V_N / 1024)
#define PADW (KPAD - V_N)    // 198

typedef __attribute__((ext_vector_type(8))) short bf16x8_t;
typedef __attribute__((ext_vector_type(4))) float f32x4_t;

static __device__ __forceinline__ unsigned short f2bf(float f) {
    union { float f; unsigned u; } v; v.f = f;
    unsigned r = v.u + 0x7fffu + ((v.u >> 16) & 1u);   // RNE
    return (unsigned short)(r >> 16);
}

// ---------------- Step 0: wfc = W @ fcW  (+ fold: zero count) (R11-verified) ------------
__global__ __launch_bounds__(256) void wfc_kernel(const float* __restrict__ W,
                                                  const float* __restrict__ fcW,
                                                  float* __restrict__ wfc,
                                                  int* __restrict__ count) {
    int gtid = blockIdx.x * 256 + threadIdx.x;
    if (gtid < V_N) count[gtid] = 0;

    __shared__ float wrow[16][128];
    int row0 = blockIdx.x * 16;
    for (int idx = threadIdx.x; idx < 16 * 32; idx += 256) {
        int r = idx >> 5, c4 = (idx & 31) * 4;
        int grow = row0 + r;
        float4 v = make_float4(0.f, 0.f, 0.f, 0.f);
        if (grow < AV_N)
            v = *reinterpret_cast<const float4*>(W + (size_t)grow * H_N + c4);
        *reinterpret_cast<float4*>(&wrow[r][c4]) = v;
    }
    __syncthreads();
    int r = threadIdx.x >> 4, o = threadIdx.x & 15;
    int grow = row0 + r;
    if (grow >= AV_N) return;
    float s = 0.f;
#pragma unroll
    for (int h = 0; h < H_N; ++h) s += wrow[r][h] * fcW[h * O_N + o];
    wfc[(size_t)grow * O_N + o] = s;
}

// ---------------- Step 1: histogram (+ fold: zero hw_t K-pad) (R11-verified) ------------
__global__ __launch_bounds__(256) void hist_kernel(const int* __restrict__ rows,
                                                   int* __restrict__ count,
                                                   short* __restrict__ hw_t) {
    int n = blockIdx.x * blockDim.x + threadIdx.x;
    if (n < O_N * PADW) {
        int o = n / PADW, v2 = V_N + (n - o * PADW);
        hw_t[(size_t)o * KPAD + v2] = 0;
    }
    if (n >= NNZ_T) return;
    atomicAdd(&count[rows[n]], 1);
}

// ---------------- Step 2a: per-1024-chunk sums (R7-verified) ----------------
__global__ __launch_bounds__(1024) void scanA_kernel(const int* __restrict__ count,
                                                     int* __restrict__ csum) {
    __shared__ int sdata[1024];
    int tid = threadIdx.x;
    int i = blockIdx.x * 1024 + tid;
    sdata[tid] = (i < V_N) ? count[i] : 0;
    __syncthreads();
    for (int off = 512; off > 0; off >>= 1) {
        if (tid < off) sdata[tid] += sdata[tid + off];
        __syncthreads();
    }
    if (tid == 0) csum[blockIdx.x] = sdata[0];
}

// ---------------- Step 2b: per-chunk exclusive scan + folded chunk-offset scan ----------
// (R14-verified)
__global__ __launch_bounds__(1024) void scanC_kernel(const int* __restrict__ count,
                                                     const int* __restrict__ csum,
                                                     int* __restrict__ row_start,
                                                     int* __restrict__ cursor) {
    __shared__ int sdata[1024];
    __shared__ int coff_s;
    int tid = threadIdx.x;
    int bid = blockIdx.x;
    if (tid < 32) {
        int own = (tid < NCHUNK) ? csum[tid] : 0;
        int v = own;
#pragma unroll
        for (int d = 1; d < 32; d <<= 1) {
            int t = __shfl_up(v, d, 32);
            if (tid >= d) v += t;
        }
        if (tid == bid) coff_s = v - own;                      // exclusive prefix
        if (bid == 0 && tid == NCHUNK - 1) row_start[V_N] = v; // total
    }
    int i = bid * 1024 + tid;
    int v = (i < V_N) ? count[i] : 0;
    sdata[tid] = v;
    __syncthreads();
    for (int off = 1; off < 1024; off <<= 1) {
        int t = (tid >= off) ? sdata[tid - off] : 0;
        __syncthreads();
        sdata[tid] += t;
        __syncthreads();
    }
    int exc = sdata[tid] - v + coff_s;
    if (i < V_N) { row_start[i] = exc; cursor[i] = exc; }
}

// ---------------- Step 3: scatter nnz, packed (colp|val) 8B stores (R8-verified) --------
__global__ __launch_bounds__(256) void scatter_kernel(const int* __restrict__ rows,
                                                      const int* __restrict__ cols,
                                                      const float* __restrict__ vals,
                                                      int* __restrict__ cursor,
                                                      unsigned long long* __restrict__ scv) {
    int n = blockIdx.x * blockDim.x + threadIdx.x;
    if (n >= NNZ_T) return;
    int a = (n >= NNZ_N) ? 1 : 0;
    int r = rows[n];
    int pos = atomicAdd(&cursor[r], 1);
    union { float f; unsigned u; } uv; uv.f = vals[n];
    scv[pos] = ((unsigned long long)uv.u << 32) | (unsigned)(a * V_N + cols[n]);
}

// ---------------- Step 4: segmented accumulate -> hw_t bf16 [16][KPAD] (R8-verified) ----
__global__ __launch_bounds__(256) void accum_hw_kernel(const int* __restrict__ row_start,
                                                       const unsigned long long* __restrict__ scv,
                                                       const float* __restrict__ wfc,
                                                       short* __restrict__ hw_t) {
    int gid = blockIdx.x * blockDim.x + threadIdx.x;
    if (gid >= V_N * O_N) return;
    int row = gid >> 4, o = gid & 15;
    int s = row_start[row];
    int e = row_start[row + 1];
    float acc = 0.f;
    for (int i = s; i < e; ++i) {
        unsigned long long cv = scv[i];
        int cp = (int)(cv & 0xffffffffu);
        union { unsigned u; float f; } uv; uv.u = (unsigned)(cv >> 32);
        acc += uv.f * wfc[(size_t)cp * O_N + o];
    }
    hw_t[(size_t)o * KPAD + row] = (short)f2bf(acc);
}

// ---------------- Step 5: streaming MFMA GEMM -> partials (R18-proven pipeline) ---------
// grid (32, KSPL=16): 512 blocks — halved stream count, doubled per-stream length.
// by<15: 3-buffer rotating SW pipeline (2 K-steps of loads in flight). by==15: checked.
__global__ __launch_bounds__(256) void gemm_mfma5(const float* __restrict__ X,
                                                  const short* __restrict__ hw_t,
                                                  float* __restrict__ partials) {
    const int tid = threadIdx.x;
    const int w = tid >> 6;
    const int lane = tid & 63;
    const int l15 = lane & 15;
    const int kg = lane >> 4;       // 0..3
    const int row0 = blockIdx.x * 64 + w * 16;
    const int by = blockIdx.y;
    const int k0 = by * KC;

    const float* xrow = X + (size_t)(row0 + l15) * V_N;
    const short* hrow = hw_t + (size_t)l15 * KPAD;

    f32x4_t acc = {};

    if (k0 + KC <= V_N) {           // by < 15: software-pipelined, branch-free
        auto LOAD4 = [&](int s, float2& c0, float2& c1, float2& c2, float2& c3) {
            const float2* p = reinterpret_cast<const float2*>(xrow + k0 + s * 32 + kg * 8);
            c0 = p[0]; c1 = p[1]; c2 = p[2]; c3 = p[3];
        };
        auto STEP = [&](int s, float2 c0, float2 c1, float2 c2, float2 c3) {
            bf16x8_t av;
            av[0] = (short)f2bf(c0.x); av[1] = (short)f2bf(c0.y);
            av[2] = (short)f2bf(c1.x); av[3] = (short)f2bf(c1.y);
            av[4] = (short)f2bf(c2.x); av[5] = (short)f2bf(c2.y);
            av[6] = (short)f2bf(c3.x); av[7] = (short)f2bf(c3.y);
            bf16x8_t bv = *reinterpret_cast<const bf16x8_t*>(hrow + k0 + s * 32 + kg * 8);
            acc = __builtin_amdgcn_mfma_f32_16x16x32_bf16(av, bv, acc, 0, 0, 0);
        };

        float2 A0, A1, A2, A3, B0, B1, B2, B3, C0, C1, C2, C3;
        LOAD4(0, A0, A1, A2, A3);
        LOAD4(1, B0, B1, B2, B3);
        LOAD4(2, C0, C1, C2, C3);
#pragma unroll 1
        for (int s = 0; s < NSTEP - 3; s += 3) {   // computes 0..NSTEP-4, loads 3..NSTEP-1
            STEP(s,     A0, A1, A2, A3); LOAD4(s + 3, A0, A1, A2, A3);
            STEP(s + 1, B0, B1, B2, B3); LOAD4(s + 4, B0, B1, B2, B3);
            STEP(s + 2, C0, C1, C2, C3); LOAD4(s + 5, C0, C1, C2, C3);
        }
        STEP(NSTEP - 3, A0, A1, A2, A3);
        STEP(NSTEP - 2, B0, B1, B2, B3);
        STEP(NSTEP - 1, C0, C1, C2, C3);
    } else {                        // by == 15: checked tail (R11-proven)
#pragma unroll 2
        for (int kb = k0; kb < k0 + KC; kb += 32) {
            int k = kb + kg * 8;
            float a[8];
            if (k + 7 < V_N) {
                const float2* p = reinterpret_cast<const float2*>(xrow + k);
                float2 u0 = p[0], u1 = p[1], u2 = p[2], u3 = p[3];
                a[0] = u0.x; a[1] = u0.y; a[2] = u1.x; a[3] = u1.y;
                a[4] = u2.x; a[5] = u2.y; a[6] = u3.x; a[7] = u3.y;
            } else {
#pragma unroll
                for (int j = 0; j < 8; ++j) a[j] = (k + j < V_N) ? xrow[k + j] : 0.f;
            }
            bf16x8_t av;
#pragma unroll
            for (int j = 0; j < 8; ++j) av[j] = (short)f2bf(a[j]);
            bf16x8_t bv = *reinterpret_cast<const bf16x8_t*>(hrow + k);
            acc = __builtin_amdgcn_mfma_f32_16x16x32_bf16(av, bv, acc, 0, 0, 0);
        }
    }

    // D layout (R5-R18 verified): col = l15, row = kg*4 + r4. Unique per (by,row) -> stores.
#pragma unroll
    for (int r4 = 0; r4 < 4; ++r4)
        partials[((size_t)by * M_N + row0 + kg * 4 + r4) * O_N + l15] = acc[r4];
}

// ---------------- Step 6: reduce split-K partials + bias -> out (R11-verified) ----------
__global__ __launch_bounds__(256) void reduce_kernel(const float* __restrict__ partials,
                                                     const float* __restrict__ fcb,
                                                     float* __restrict__ out) {
    int idx = blockIdx.x * 256 + threadIdx.x;   // 0 .. M_N*O_N-1
    if (idx >= M_N * O_N) return;
    float s = fcb[idx & 15];
#pragma unroll
    for (int by = 0; by < KSPL; ++by)
        s += partials[(size_t)by * M_N * O_N + idx];
    out[idx] = s;
}

extern "C" void kernel_launch(void* const* d_in, const int* in_sizes, int n_in,
                              void* d_out, int out_size, void* d_ws, size_t ws_size,
                              hipStream_t stream) {
    const float* x    = (const float*)d_in[0];
    const int* rows   = (const int*)d_in[1];
    const int* cols   = (const int*)d_in[2];
    const float* vals = (const float*)d_in[3];
    const float* W    = (const float*)d_in[4];
    const float* fcW  = (const float*)d_in[5];
    const float* fcb  = (const float*)d_in[6];
    float* out = (float*)d_out;

    char* base = (char*)d_ws;
    size_t off = 0;
    auto alloc = [&](size_t bytes) { size_t p = off; off = (off + bytes + 255) & ~(size_t)255; return p; };
    size_t o_wfc    = alloc((size_t)AV_N * O_N * 4);
    size_t o_hwt    = alloc((size_t)O_N * KPAD * 2);
    size_t o_count  = alloc((size_t)V_N * 4);
    size_t o_rstart = alloc((size_t)(V_N + 1) * 4);
    size_t o_cursor = alloc((size_t)V_N * 4);
    size_t o_scv    = alloc((size_t)NNZ_T * 8);
    size_t o_csum   = alloc((size_t)NCHUNK * 4);
    size_t o_part   = alloc((size_t)KSPL * M_N * O_N * 4);

    float* wfc        = (float*)(base + o_wfc);
    short* hw_t       = (short*)(base + o_hwt);
    int*   count      = (int*)(base + o_count);
    int*   row_start  = (int*)(base + o_rstart);
    int*   cursor     = (int*)(base + o_cursor);
    unsigned long long* scv = (unsigned long long*)(base + o_scv);
    int*   csum       = (int*)(base + o_csum);
    float* partials   = (float*)(base + o_part);

    wfc_kernel<<<(AV_N + 15) / 16, 256, 0, stream>>>(W, fcW, wfc, count);
    hist_kernel<<<(NNZ_T + 255) / 256, 256, 0, stream>>>(rows, count, hw_t);
    scanA_kernel<<<NCHUNK, 1024, 0, stream>>>(count, csum);
    scanC_kernel<<<NCHUNK, 1024, 0, stream>>>(count, csum, row_start, cursor);
    scatter_kernel<<<(NNZ_T + 255) / 256, 256, 0, stream>>>(rows, cols, vals, cursor, scv);
    accum_hw_kernel<<<(V_N * O_N + 255) / 256, 256, 0, stream>>>(row_start, scv, wfc, hw_t);

    gemm_mfma5<<<dim3(M_N / 64, KSPL), 256, 0, stream>>>(x, hw_t, partials);
    reduce_kernel<<<(M_N * O_N + 255) / 256, 256, 0, stream>>>(partials, fcb, out);
}